// Round 10
// baseline (215.060 us; speedup 1.0000x reference)
//
#include <hip/hip_runtime.h>
#include <stdint.h>

#define BSZ  4
#define NSEQ 2048
#define DM   128
#define NH   8
#define DK   16
#define LOG2E 1.4426950408889634f
// LOG2E / sqrt(128): folded into Wq/bq so scores exit QK^T in log2 domain
#define SCALE_QL 0.1275156338341935f
// mask weight: w = mask * 2^-18 (exact in bf16); folded into V' and the
// l-reduction A-operand. p = exp2(S) stays <= ~2^10, l ~ 1e-2 -> safe fp32.
#define W_SCALE 3.814697265625e-6f

typedef __bf16          bf16x8v __attribute__((ext_vector_type(8)));
typedef float           f32x4   __attribute__((ext_vector_type(4)));
typedef float           f32x16  __attribute__((ext_vector_type(16)));
typedef unsigned short  u16x8   __attribute__((ext_vector_type(8)));
typedef unsigned short  u16x4   __attribute__((ext_vector_type(4)));
typedef unsigned int    u32x2   __attribute__((ext_vector_type(2)));
typedef unsigned int    u32x4   __attribute__((ext_vector_type(4)));

__device__ __forceinline__ unsigned short f2bf(float f) {
    unsigned u = __float_as_uint(f);
    u = (u + 0x7fffu + ((u >> 16) & 1u)) >> 16;
    return (unsigned short)u;
}

__device__ __forceinline__ unsigned int pack2bf(float a, float b) {
#if __has_builtin(__builtin_amdgcn_cvt_pk_bf16_f32)
    typedef __bf16 bf16x2 __attribute__((ext_vector_type(2)));
    bf16x2 v = __builtin_amdgcn_cvt_pk_bf16_f32(a, b);
    return __builtin_bit_cast(unsigned int, v);
#else
    return (unsigned)f2bf(a) | ((unsigned)f2bf(b) << 16);
#endif
}

__device__ __forceinline__ float exp2_(float x) {
#if __has_builtin(__builtin_amdgcn_exp2f)
    return __builtin_amdgcn_exp2f(x);
#else
    return exp2f(x);
#endif
}

// load 8 consecutive f32, scale, convert -> u16x8 bf16 fragment
__device__ __forceinline__ u16x8 cvt8(const float* p, float sc) {
    const f32x4 a = *reinterpret_cast<const f32x4*>(p);
    const f32x4 b = *reinterpret_cast<const f32x4*>(p + 4);
    u32x4 u = {pack2bf(a[0] * sc, a[1] * sc), pack2bf(a[2] * sc, a[3] * sc),
               pack2bf(b[0] * sc, b[1] * sc), pack2bf(b[2] * sc, b[3] * sc)};
    return __builtin_bit_cast(u16x8, u);
}

__device__ __forceinline__ f32x4 mfma16(u16x8 a, u16x8 b, f32x4 c) {
    return __builtin_amdgcn_mfma_f32_16x16x32_bf16(
        __builtin_bit_cast(bf16x8v, a), __builtin_bit_cast(bf16x8v, b), c, 0, 0, 0);
}
__device__ __forceinline__ f32x16 mfma32(u16x8 a, u16x8 b, f32x16 c) {
    return __builtin_amdgcn_mfma_f32_32x32x16_bf16(
        __builtin_bit_cast(bf16x8v, a), __builtin_bit_cast(bf16x8v, b), c, 0, 0, 0);
}

// ---------------------------------------------------------------------------
// k_qkv: C^T-form projection, x-tile staged in LDS (coalesced f32x4 loads).
// grid = b(4) x n-tile32(64), 768 threads = 12 waves = mat(3) x nsub(2) x th(2).
// V is scaled by w = mask*2^-18 at generation (V' = V*w).
// Side-job: WfcB = bf16(Wfc); wb = bf16(mask*2^-18).
// ---------------------------------------------------------------------------
__global__ __launch_bounds__(768) void k_qkv(
    const float* __restrict__ x,
    const float* __restrict__ Wq, const float* __restrict__ bq,
    const float* __restrict__ Wk, const float* __restrict__ bk,
    const float* __restrict__ Wv, const float* __restrict__ bv,
    const float* __restrict__ Wfc, const float* __restrict__ mask,
    unsigned short* __restrict__ Q, unsigned short* __restrict__ Kb,
    unsigned short* __restrict__ Vt,
    unsigned short* __restrict__ WfcB, unsigned short* __restrict__ wb)
{
    __shared__ __align__(16) float xs[DM * 36];   // 32 n + 4 pad
    const int tid = threadIdx.x;

    // side job (consumed by LATER kernels only)
    const int gt = blockIdx.x * 768 + tid;
    if (gt < DM * DM) {
        WfcB[gt] = f2bf(Wfc[gt]);
    } else if (gt < DM * DM + BSZ * NSEQ) {
        const int i = gt - DM * DM;
        wb[i] = f2bf(mask[i] * W_SCALE);
    }

    const int b  = blockIdx.x >> 6;
    const int n0 = (blockIdx.x & 63) << 5;

    // stage x[b][0..128][n0..n0+32] -> xs[d*36 + j], fully coalesced
#pragma unroll
    for (int i = tid; i < 1024; i += 768) {
        const int d = i >> 3, c4 = (i & 7) << 2;
        *reinterpret_cast<f32x4*>(&xs[d * 36 + c4]) =
            *reinterpret_cast<const f32x4*>(x + (size_t)(b * DM + d) * NSEQ + n0 + c4);
    }
    __syncthreads();

    const int lane = tid & 63;
    const int wv   = tid >> 6;          // 0..11
    const int mat  = wv >> 2;           // 0..2
    const int nt   = (wv >> 1) & 1;     // n subtile
    const int th   = wv & 1;            // t half
    const int c    = lane & 15;
    const int quad = lane >> 4;
    const int col  = n0 + nt * 16 + c;

    // B-frag from LDS: B[k=d][n=c]
    u16x8 xf[4];
#pragma unroll
    for (int kk = 0; kk < 4; ++kk) {
        float f[8];
#pragma unroll
        for (int j = 0; j < 8; ++j)
            f[j] = xs[(kk * 32 + quad * 8 + j) * 36 + nt * 16 + c];
        u32x4 u = {pack2bf(f[0], f[1]), pack2bf(f[2], f[3]),
                   pack2bf(f[4], f[5]), pack2bf(f[6], f[7])};
        xf[kk] = __builtin_bit_cast(u16x8, u);
    }

    const float* W    = (mat == 0) ? Wq : (mat == 1) ? Wk : Wv;
    const float* bias = (mat == 0) ? bq : (mat == 1) ? bk : bv;
    const float  sc   = (mat == 0) ? SCALE_QL : 1.0f;
    const float  vw   = (mat == 2) ? mask[b * NSEQ + col] * W_SCALE : 0.f;

#pragma unroll
    for (int tt = 0; tt < 4; ++tt) {
        const int t = th * 4 + tt;
        f32x4 acc = {0.f, 0.f, 0.f, 0.f};
#pragma unroll
        for (int kk = 0; kk < 4; ++kk)
            acc = mfma16(cvt8(W + (t * 16 + c) * DM + kk * 32 + quad * 8, sc),
                         xf[kk], acc);
        if (mat == 2) {
#pragma unroll
            for (int r = 0; r < 4; ++r)
                Vt[((b * NH + t) * DK + quad * 4 + r) * NSEQ + col] =
                    f2bf((acc[r] + bias[t * 16 + quad * 4 + r]) * vw);
        } else {
            u16x4 pk;
#pragma unroll
            for (int r = 0; r < 4; ++r)
                pk[r] = f2bf(acc[r] + bias[t * 16 + quad * 4 + r] * sc);
            *reinterpret_cast<u16x4*>(
                (mat == 0 ? Q : Kb) + ((size_t)(b * NH + t) * NSEQ + col) * DK +
                quad * 4) = pk;
        }
    }
}

// ---------------------------------------------------------------------------
// k_attn v4: R6 fixed-scale flash attention + FUSED FC via last-arriver.
// Block = one 32-query tile (b,h,n32). After writing AO, block atomically
// incs cnt[b][n32]; the 8th arriver (all heads done for these 32 columns)
// performs the FC for its 32 columns, reading AO warm from L2/L3.
// Release: __syncthreads (vmcnt drain) + one __threadfence (L2 wb).
// Acquire: one __threadfence in finisher. No spinning anywhere.
// ---------------------------------------------------------------------------
__global__ __launch_bounds__(256, 4) void k_attn(
    const unsigned short* __restrict__ Q,
    const unsigned short* __restrict__ Kb,
    const unsigned short* __restrict__ Vt,
    const unsigned short* __restrict__ wb,
    const unsigned short* __restrict__ WfcB,
    const float* __restrict__ bfc,
    unsigned short* __restrict__ AO,
    float* __restrict__ out,
    unsigned* __restrict__ cnt)
{
    __shared__ __align__(16) char smem[17408];
    __shared__ int fcflag;
    const int tid  = threadIdx.x;
    const int lane = tid & 63;
    const int w    = tid >> 6;      // kv quarter
    const int q32  = lane & 31;
    const int c    = lane & 15;
    const int quad = lane >> 4;
    const int hi   = lane >> 5;

    const int b  = blockIdx.x >> 9;
    const int h  = (blockIdx.x >> 6) & 7;
    const int n0 = (blockIdx.x & 63) << 5;
    const int bh = b * NH + h;

    // Q B-frag (prescaled to log2 domain): B[k=8*hi+j][n=q32]
    const u16x8 uq = *reinterpret_cast<const u16x8*>(
        Q + ((size_t)bh * NSEQ + n0 + q32) * DK + 8 * hi);

    const unsigned short* Kp = Kb + (size_t)bh * NSEQ * DK + 8 * hi;
    const unsigned short* Vp = Vt + ((size_t)bh * DK + c) * NSEQ + 8 * quad;
    const unsigned short* wp = wb + b * NSEQ + 8 * quad;

    // per-wave P staging: 32 rows (q) x 136 B (64 kv bf16 + 8B pad)
    char* pbase = smem + w * 4352;
    char* wrow  = pbase + q32 * 136 + 8 * hi;
    const char* rrow0 = pbase + c * 136 + 16 * quad;
    const char* rrow1 = pbase + (c + 16) * 136 + 16 * quad;

    f32x4 o0 = {0.f, 0.f, 0.f, 0.f}, o1 = {0.f, 0.f, 0.f, 0.f};
    f32x4 l0 = {0.f, 0.f, 0.f, 0.f}, l1 = {0.f, 0.f, 0.f, 0.f};
    const f32x16 z16 = {};
    const int kvb = w * (NSEQ / 4);

    // prefetch iteration 0's K fragments
    u16x8 nk0 = *reinterpret_cast<const u16x8*>(Kp + (size_t)(kvb + q32) * DK);
    u16x8 nk1 = *reinterpret_cast<const u16x8*>(Kp + (size_t)(kvb + 32 + q32) * DK);

    for (int it = 0; it < 8; ++it) {
        const int kv0 = kvb + it * 64;
        const u16x8 uk0 = nk0, uk1 = nk1;
        if (it < 7) {
            nk0 = *reinterpret_cast<const u16x8*>(Kp + (size_t)(kv0 + 64 + q32) * DK);
            nk1 = *reinterpret_cast<const u16x8*>(Kp + (size_t)(kv0 + 96 + q32) * DK);
        }
        f32x16 S0 = mfma32(uk0, uq, z16);   // S^T[kv][q] (log2 domain)
        f32x16 S1 = mfma32(uk1, uq, z16);

        // p = exp2(S)
#pragma unroll
        for (int i = 0; i < 16; ++i) {
            S0[i] = exp2_(S0[i]);
            S1[i] = exp2_(S1[i]);
        }

        // stage P[q][kv] to LDS (packed bf16)
#pragma unroll
        for (int g = 0; g < 4; ++g) {
            u32x2 d0 = {pack2bf(S0[4 * g], S0[4 * g + 1]),
                        pack2bf(S0[4 * g + 2], S0[4 * g + 3])};
            u32x2 d1 = {pack2bf(S1[4 * g], S1[4 * g + 1]),
                        pack2bf(S1[4 * g + 2], S1[4 * g + 3])};
            *reinterpret_cast<u32x2*>(wrow + 16 * g) = d0;
            *reinterpret_cast<u32x2*>(wrow + 64 + 16 * g) = d1;
        }

        // PV + l: 2 rounds of K=32 kv (unnormalized; w folded into V' and uw)
#pragma unroll
        for (int t = 0; t < 2; ++t) {
            const u16x8 uv  = *reinterpret_cast<const u16x8*>(Vp + kv0 + 32 * t);
            const u16x8 uw  = *reinterpret_cast<const u16x8*>(wp + kv0 + 32 * t);
            const u16x8 up0 = *reinterpret_cast<const u16x8*>(rrow0 + 64 * t);
            const u16x8 up1 = *reinterpret_cast<const u16x8*>(rrow1 + 64 * t);
            o0 = mfma16(uv, up0, o0);   // O^T[dk][q=c]
            o1 = mfma16(uv, up1, o1);   // q = 16+c
            l0 = mfma16(uw, up0, l0);   // all rows = sum_kv w*p (q=c)
            l1 = mfma16(uw, up1, l1);   // q = 16+c
        }
    }

    // ---- plain-sum 4-way merge (reuse P-staging LDS) ----
    __syncthreads();                       // all P reads done
    float* Lsm = reinterpret_cast<float*>(smem);          // [w][q] l partials
    float* Osm = reinterpret_cast<float*>(smem + 512);    // [w][q*20 + dk]
    Lsm[w * 32 + c]      = l0[0];          // all quads hold same value
    Lsm[w * 32 + 16 + c] = l1[0];
    *reinterpret_cast<f32x4*>(Osm + w * 640 + c * 20 + 4 * quad)        = o0;
    *reinterpret_cast<f32x4*>(Osm + w * 640 + (c + 16) * 20 + 4 * quad) = o1;
    __syncthreads();

    const int q   = tid >> 3;              // 0..31
    const int dk2 = (tid & 7) * 2;         // 0,2,..,14
    const float l = Lsm[q] + Lsm[32 + q] + Lsm[64 + q] + Lsm[96 + q];
    const float* Oq = Osm + q * 20 + dk2;
    const float v0 = Oq[0] + Oq[640] + Oq[1280] + Oq[1920];
    const float v1 = Oq[1] + Oq[641] + Oq[1281] + Oq[1921];
    const float inv = 1.0f / l;
    *reinterpret_cast<unsigned int*>(
        AO + ((size_t)(b * NSEQ) + n0 + q) * DM + h * DK + dk2) =
        pack2bf(v0 * inv, v1 * inv);

    // ================= fused FC: last-arriver per (b, n32) =================
    __syncthreads();   // emits s_waitcnt vmcnt(0) before s_barrier: AO stores
                       // of ALL threads of this block are complete at L2
    if (tid == 0) {
        __threadfence();   // release: L2 writeback (publishes AO cross-XCD)
        const unsigned old = __hip_atomic_fetch_add(
            &cnt[b * 64 + (blockIdx.x & 63)], 1u,
            __ATOMIC_RELAXED, __HIP_MEMORY_SCOPE_AGENT);
        fcflag = (old == NH - 1);
    }
    __syncthreads();
    if (!fcflag) return;

    __threadfence();       // acquire: invalidate stale L1/L2 once
    // FC for columns n0..n0+31: out[b][128 d'][32 n].
    // wave w -> d'-tiles {2w, 2w+1}; 2 n-subtiles of 16.
#pragma unroll
    for (int ns = 0; ns < 2; ++ns) {
        const int nc = n0 + ns * 16 + c;
        u16x8 af[4];
#pragma unroll
        for (int kk = 0; kk < 4; ++kk)
            af[kk] = *reinterpret_cast<const u16x8*>(
                AO + ((size_t)(b * NSEQ) + nc) * DM + kk * 32 + quad * 8);
#pragma unroll
        for (int tt = 0; tt < 2; ++tt) {
            const int t = w * 2 + tt;
            f32x4 acc = {0.f, 0.f, 0.f, 0.f};
#pragma unroll
            for (int kk = 0; kk < 4; ++kk)
                acc = mfma16(*reinterpret_cast<const u16x8*>(
                                 WfcB + (t * 16 + c) * DM + kk * 32 + quad * 8),
                             af[kk], acc);
#pragma unroll
            for (int r = 0; r < 4; ++r)
                out[(size_t)(b * DM + t * 16 + quad * 4 + r) * NSEQ + nc] =
                    acc[r] + bfc[t * 16 + quad * 4 + r];
        }
    }
}

// ---------------------------------------------------------------------------
extern "C" void kernel_launch(void* const* d_in, const int* in_sizes, int n_in,
                              void* d_out, int out_size, void* d_ws, size_t ws_size,
                              hipStream_t stream)
{
    const float* x    = (const float*)d_in[0];
    const float* mask = (const float*)d_in[1];
    const float* Wq   = (const float*)d_in[2];
    const float* bq   = (const float*)d_in[3];
    const float* Wk   = (const float*)d_in[4];
    const float* bk   = (const float*)d_in[5];
    const float* Wv   = (const float*)d_in[6];
    const float* bv   = (const float*)d_in[7];
    const float* Wfc  = (const float*)d_in[8];
    const float* bfc  = (const float*)d_in[9];
    float* out = (float*)d_out;

    const size_t QKV_ELEMS = (size_t)BSZ * NH * NSEQ * DK;  // 1,048,576
    unsigned short* Q    = (unsigned short*)d_ws;
    unsigned short* Kb   = Q + QKV_ELEMS;
    unsigned short* Vt   = Kb + QKV_ELEMS;
    unsigned short* AO   = Vt + QKV_ELEMS;
    unsigned short* WfcB = AO + QKV_ELEMS;
    unsigned short* wb   = WfcB + DM * DM;
    unsigned*       cnt  = (unsigned*)(wb + BSZ * NSEQ);   // 256 counters

    hipMemsetAsync(cnt, 0, 256 * sizeof(unsigned), stream);
    k_qkv<<<256, 768, 0, stream>>>(x, Wq, bq, Wk, bk, Wv, bv, Wfc, mask,
                                   Q, Kb, Vt, WfcB, wb);
    k_attn<<<2048, 256, 0, stream>>>(Q, Kb, Vt, wb, WfcB, bfc, AO, out, cnt);
}

// Round 11
// 132.416 us; speedup vs baseline: 1.6241x; 1.6241x over previous
//
#include <hip/hip_runtime.h>
#include <stdint.h>

#define BSZ  4
#define NSEQ 2048
#define DM   128
#define NH   8
#define DK   16
#define LOG2E 1.4426950408889634f
// LOG2E / sqrt(128): folded into Wq/bq so scores exit QK^T in log2 domain
#define SCALE_QL 0.1275156338341935f
// mask weight: w = mask * 2^-18 (exact in bf16); folded into V' (rows 0-15 of
// VW) and the l row (row 16 of VW). p = exp2(S) <= ~2^10, l ~ 1e-2 -> safe.
#define W_SCALE 3.814697265625e-6f

typedef __bf16          bf16x8v __attribute__((ext_vector_type(8)));
typedef float           f32x4   __attribute__((ext_vector_type(4)));
typedef float           f32x16  __attribute__((ext_vector_type(16)));
typedef unsigned short  u16x8   __attribute__((ext_vector_type(8)));
typedef unsigned short  u16x4   __attribute__((ext_vector_type(4)));
typedef unsigned int    u32x4   __attribute__((ext_vector_type(4)));

__device__ __forceinline__ unsigned short f2bf(float f) {
    unsigned u = __float_as_uint(f);
    u = (u + 0x7fffu + ((u >> 16) & 1u)) >> 16;
    return (unsigned short)u;
}

__device__ __forceinline__ unsigned int pack2bf(float a, float b) {
#if __has_builtin(__builtin_amdgcn_cvt_pk_bf16_f32)
    typedef __bf16 bf16x2 __attribute__((ext_vector_type(2)));
    bf16x2 v = __builtin_amdgcn_cvt_pk_bf16_f32(a, b);
    return __builtin_bit_cast(unsigned int, v);
#else
    return (unsigned)f2bf(a) | ((unsigned)f2bf(b) << 16);
#endif
}

__device__ __forceinline__ float exp2_(float x) {
#if __has_builtin(__builtin_amdgcn_exp2f)
    return __builtin_amdgcn_exp2f(x);
#else
    return exp2f(x);
#endif
}

// load 8 consecutive f32, scale, convert -> u16x8 bf16 fragment
__device__ __forceinline__ u16x8 cvt8(const float* p, float sc) {
    const f32x4 a = *reinterpret_cast<const f32x4*>(p);
    const f32x4 b = *reinterpret_cast<const f32x4*>(p + 4);
    u32x4 u = {pack2bf(a[0] * sc, a[1] * sc), pack2bf(a[2] * sc, a[3] * sc),
               pack2bf(b[0] * sc, b[1] * sc), pack2bf(b[2] * sc, b[3] * sc)};
    return __builtin_bit_cast(u16x8, u);
}

__device__ __forceinline__ f32x4 mfma16(u16x8 a, u16x8 b, f32x4 c) {
    return __builtin_amdgcn_mfma_f32_16x16x32_bf16(
        __builtin_bit_cast(bf16x8v, a), __builtin_bit_cast(bf16x8v, b), c, 0, 0, 0);
}
__device__ __forceinline__ f32x16 mfma32(u16x8 a, u16x8 b, f32x16 c) {
    return __builtin_amdgcn_mfma_f32_32x32x16_bf16(
        __builtin_bit_cast(bf16x8v, a), __builtin_bit_cast(bf16x8v, b), c, 0, 0, 0);
}

// ---------------------------------------------------------------------------
// k_qkv: C^T-form projection, x-tile staged in LDS (coalesced f32x4 loads).
// grid = b(4) x n-tile32(64), 768 threads = 12 waves = mat(3) x nsub(2) x th(2).
// Q,K -> [B][H][N][16] bf16.
// VW   -> [B][H][32][N] bf16: rows 0-15 = V'^T = (V*w)^T, row 16 = w,
//         rows 17-31 = untouched poison (feeds never-read MFMA C rows; the
//         poison pattern 0xAAAA is a tiny finite bf16 -> no NaN/inf risk).
// Side-job: WfcB = bf16(Wfc).
// ---------------------------------------------------------------------------
__global__ __launch_bounds__(768) void k_qkv(
    const float* __restrict__ x,
    const float* __restrict__ Wq, const float* __restrict__ bq,
    const float* __restrict__ Wk, const float* __restrict__ bk,
    const float* __restrict__ Wv, const float* __restrict__ bv,
    const float* __restrict__ Wfc, const float* __restrict__ mask,
    unsigned short* __restrict__ Q, unsigned short* __restrict__ Kb,
    unsigned short* __restrict__ VW,
    unsigned short* __restrict__ WfcB)
{
    __shared__ __align__(16) float xs[DM * 36];   // 32 n + 4 pad
    const int tid = threadIdx.x;

    // side job (consumed by LATER kernels only)
    const int gt = blockIdx.x * 768 + tid;
    if (gt < DM * DM) WfcB[gt] = f2bf(Wfc[gt]);

    const int b  = blockIdx.x >> 6;
    const int n0 = (blockIdx.x & 63) << 5;

    // stage x[b][0..128][n0..n0+32] -> xs[d*36 + j], fully coalesced
#pragma unroll
    for (int i = tid; i < 1024; i += 768) {
        const int d = i >> 3, c4 = (i & 7) << 2;
        *reinterpret_cast<f32x4*>(&xs[d * 36 + c4]) =
            *reinterpret_cast<const f32x4*>(x + (size_t)(b * DM + d) * NSEQ + n0 + c4);
    }
    __syncthreads();

    const int lane = tid & 63;
    const int wv   = tid >> 6;          // 0..11
    const int mat  = wv >> 2;           // 0..2
    const int nt   = (wv >> 1) & 1;     // n subtile
    const int th   = wv & 1;            // t half
    const int c    = lane & 15;
    const int quad = lane >> 4;
    const int col  = n0 + nt * 16 + c;

    // B-frag from LDS: B[k=d][n=c]
    u16x8 xf[4];
#pragma unroll
    for (int kk = 0; kk < 4; ++kk) {
        float f[8];
#pragma unroll
        for (int j = 0; j < 8; ++j)
            f[j] = xs[(kk * 32 + quad * 8 + j) * 36 + nt * 16 + c];
        u32x4 u = {pack2bf(f[0], f[1]), pack2bf(f[2], f[3]),
                   pack2bf(f[4], f[5]), pack2bf(f[6], f[7])};
        xf[kk] = __builtin_bit_cast(u16x8, u);
    }

    const float* W    = (mat == 0) ? Wq : (mat == 1) ? Wk : Wv;
    const float* bias = (mat == 0) ? bq : (mat == 1) ? bk : bv;
    const float  sc   = (mat == 0) ? SCALE_QL : 1.0f;
    const float  vw   = (mat == 2) ? mask[b * NSEQ + col] * W_SCALE : 0.f;

#pragma unroll
    for (int tt = 0; tt < 4; ++tt) {
        const int t = th * 4 + tt;
        f32x4 acc = {0.f, 0.f, 0.f, 0.f};
#pragma unroll
        for (int kk = 0; kk < 4; ++kk)
            acc = mfma16(cvt8(W + (t * 16 + c) * DM + kk * 32 + quad * 8, sc),
                         xf[kk], acc);
        if (mat == 2) {
#pragma unroll
            for (int r = 0; r < 4; ++r)
                VW[((size_t)(b * NH + t) * 32 + quad * 4 + r) * NSEQ + col] =
                    f2bf((acc[r] + bias[t * 16 + quad * 4 + r]) * vw);
            if (quad == 0)   // w row (row 16), one writer per column
                VW[((size_t)(b * NH + t) * 32 + 16) * NSEQ + col] = f2bf(vw);
        } else {
            u16x4 pk;
#pragma unroll
            for (int r = 0; r < 4; ++r)
                pk[r] = f2bf(acc[r] + bias[t * 16 + quad * 4 + r] * sc);
            *reinterpret_cast<u16x4*>(
                (mat == 0 ? Q : Kb) + ((size_t)(b * NH + t) * NSEQ + col) * DK +
                quad * 4) = pk;
        }
    }
}

// ---------------------------------------------------------------------------
// k_attn v5: fixed-scale flash attention, NO LDS in the K-loop.
// P^T (C-layout, col=q=lane&31) -> B-operand (n=lane&31) needs only a
// half-wave swap of 2/4 packed regs per 16-kv chunk: 4 shfl_xor(32) + 4
// cndmask. PV is mfma_32x32x16 with A = VW (V' rows 0-15, w row 16) so the
// l-reduction rides in the same MFMA (D row 16). Rows 17-31 of D accumulate
// garbage and are never read. LDS only for the 4-way kv-quarter merge.
// ---------------------------------------------------------------------------
__global__ __launch_bounds__(256, 4) void k_attn(
    const unsigned short* __restrict__ Q,
    const unsigned short* __restrict__ Kb,
    const unsigned short* __restrict__ VW,
    unsigned short* __restrict__ AO)
{
    __shared__ float Lsm[128];            // [w][q]
    __shared__ __align__(16) float Osm[4 * 640];   // [w][q*20 + dk]
    const int tid  = threadIdx.x;
    const int lane = tid & 63;
    const int w    = tid >> 6;      // kv quarter
    const int q32  = lane & 31;
    const int hi   = lane >> 5;

    const int b  = blockIdx.x >> 9;
    const int h  = (blockIdx.x >> 6) & 7;
    const int n0 = (blockIdx.x & 63) << 5;
    const int bh = b * NH + h;

    // Q B-frag (prescaled to log2 domain): B[k=8*hi+j][n=q32]
    const u16x8 uq = *reinterpret_cast<const u16x8*>(
        Q + ((size_t)bh * NSEQ + n0 + q32) * DK + 8 * hi);

    const unsigned short* Kp = Kb + (size_t)bh * NSEQ * DK + 8 * hi;
    // A-operand rows: m = lane&31 -> V' dk rows 0-15, w row 16, 17-31 junk
    const unsigned short* Ap =
        VW + ((size_t)bh * 32 + q32) * NSEQ + 8 * hi;

    f32x16 D = {};                         // O rows 0-15, l row 16 (reg 8, hi=0)
    const f32x16 z16 = {};
    const int kvb = w * (NSEQ / 4);

    // prefetch iteration 0's K fragments
    u16x8 nk0 = *reinterpret_cast<const u16x8*>(Kp + (size_t)(kvb + q32) * DK);
    u16x8 nk1 = *reinterpret_cast<const u16x8*>(Kp + (size_t)(kvb + 32 + q32) * DK);

    for (int it = 0; it < 8; ++it) {
        const int kv0 = kvb + it * 64;
        const u16x8 uk0 = nk0, uk1 = nk1;
        if (it < 7) {
            nk0 = *reinterpret_cast<const u16x8*>(Kp + (size_t)(kv0 + 64 + q32) * DK);
            nk1 = *reinterpret_cast<const u16x8*>(Kp + (size_t)(kv0 + 96 + q32) * DK);
        }
        // A-frags for the 4 PV chunks (independent; in flight over the exps)
        u16x8 av[4];
#pragma unroll
        for (int cc = 0; cc < 4; ++cc)
            av[cc] = *reinterpret_cast<const u16x8*>(Ap + kv0 + 16 * cc);

        f32x16 S0 = mfma32(uk0, uq, z16);   // S^T[kv][q] (log2 domain)
        f32x16 S1 = mfma32(uk1, uq, z16);

        // p = exp2(S); pack pairs (consecutive kv) to bf16x2
        unsigned int pk[16];
#pragma unroll
        for (int i = 0; i < 8; ++i) {
            const float a0 = exp2_(S0[2 * i]),     a1 = exp2_(S0[2 * i + 1]);
            const float b0 = exp2_(S1[2 * i]),     b1 = exp2_(S1[2 * i + 1]);
            pk[i]     = pack2bf(a0, a1);
            pk[8 + i] = pack2bf(b0, b1);
        }

        // 4 chunks of 16 kv: in-register transpose to B-operand layout
#pragma unroll
        for (int cc = 0; cc < 4; ++cc) {
            const unsigned int q0 = pk[4 * cc + 0], q1 = pk[4 * cc + 1];
            const unsigned int q2 = pk[4 * cc + 2], q3 = pk[4 * cc + 3];
            const unsigned int t0 = (unsigned)__shfl_xor((int)q0, 32, 64);
            const unsigned int t1 = (unsigned)__shfl_xor((int)q1, 32, 64);
            const unsigned int t2 = (unsigned)__shfl_xor((int)q2, 32, 64);
            const unsigned int t3 = (unsigned)__shfl_xor((int)q3, 32, 64);
            u32x4 bf = {hi ? t2 : q0, hi ? t3 : q1,
                        hi ? q2 : t0, hi ? q3 : t1};
            D = mfma32(av[cc], __builtin_bit_cast(u16x8, bf), D);
        }
    }

    // ---- plain-sum 4-way merge across kv quarters ----
    if (!hi) Lsm[w * 32 + q32] = D[8];     // l = row 16, lanes 0-31
    *reinterpret_cast<f32x4*>(&Osm[w * 640 + q32 * 20 + 4 * hi]) =
        f32x4{D[0], D[1], D[2], D[3]};     // dk rows 4hi+0..3
    *reinterpret_cast<f32x4*>(&Osm[w * 640 + q32 * 20 + 8 + 4 * hi]) =
        f32x4{D[4], D[5], D[6], D[7]};     // dk rows 8+4hi+0..3
    __syncthreads();

    const int q   = tid >> 3;              // 0..31
    const int dk2 = (tid & 7) * 2;         // 0,2,..,14
    const float l = Lsm[q] + Lsm[32 + q] + Lsm[64 + q] + Lsm[96 + q];
    const float* Oq = Osm + q * 20 + dk2;
    const float v0 = Oq[0] + Oq[640] + Oq[1280] + Oq[1920];
    const float v1 = Oq[1] + Oq[641] + Oq[1281] + Oq[1921];
    const float inv = 1.0f / l;
    *reinterpret_cast<unsigned int*>(
        AO + ((size_t)(b * NSEQ) + n0 + q) * DM + h * DK + dk2) =
        pack2bf(v0 * inv, v1 * inv);
}

// ---------------------------------------------------------------------------
// k_fc: C^T-form FC, output directly in (B, D, N).
// grid = b(4) x n-tile(128) x t-half(2), 4 waves, wave = one d'-tile.
// ---------------------------------------------------------------------------
__global__ __launch_bounds__(256) void k_fc(
    const unsigned short* __restrict__ AO,
    const unsigned short* __restrict__ WfcB, const float* __restrict__ bfc,
    float* __restrict__ out)
{
    const int lane = threadIdx.x & 63;
    const int w    = threadIdx.x >> 6;
    const int c    = lane & 15;
    const int quad = lane >> 4;
    const int b    = blockIdx.x >> 8;
    const int n0   = ((blockIdx.x >> 1) & 127) << 4;
    const int t    = (blockIdx.x & 1) * 4 + w;

    u16x8 af[4];
#pragma unroll
    for (int kk = 0; kk < 4; ++kk)
        af[kk] = *reinterpret_cast<const u16x8*>(
            AO + ((size_t)(b * NSEQ) + n0 + c) * DM + kk * 32 + quad * 8);

    f32x4 acc = {0.f, 0.f, 0.f, 0.f};
#pragma unroll
    for (int kk = 0; kk < 4; ++kk)
        acc = mfma16(*reinterpret_cast<const u16x8*>(
                         WfcB + (t * 16 + c) * DM + kk * 32 + quad * 8),
                     af[kk], acc);
#pragma unroll
    for (int r = 0; r < 4; ++r)
        out[(size_t)(b * DM + t * 16 + quad * 4 + r) * NSEQ + n0 + c] =
            acc[r] + bfc[t * 16 + quad * 4 + r];
}

// ---------------------------------------------------------------------------
extern "C" void kernel_launch(void* const* d_in, const int* in_sizes, int n_in,
                              void* d_out, int out_size, void* d_ws, size_t ws_size,
                              hipStream_t stream)
{
    const float* x    = (const float*)d_in[0];
    const float* mask = (const float*)d_in[1];
    const float* Wq   = (const float*)d_in[2];
    const float* bq   = (const float*)d_in[3];
    const float* Wk   = (const float*)d_in[4];
    const float* bk   = (const float*)d_in[5];
    const float* Wv   = (const float*)d_in[6];
    const float* bv   = (const float*)d_in[7];
    const float* Wfc  = (const float*)d_in[8];
    const float* bfc  = (const float*)d_in[9];
    float* out = (float*)d_out;

    const size_t QKV_ELEMS = (size_t)BSZ * NH * NSEQ * DK;  // 1,048,576
    unsigned short* Q    = (unsigned short*)d_ws;
    unsigned short* Kb   = Q + QKV_ELEMS;
    unsigned short* VW   = Kb + QKV_ELEMS;          // [B][H][32][N] = 2*QKV
    unsigned short* AO   = VW + 2 * QKV_ELEMS;
    unsigned short* WfcB = AO + QKV_ELEMS;

    k_qkv<<<256, 768, 0, stream>>>(x, Wq, bq, Wk, bk, Wv, bv, Wfc, mask,
                                   Q, Kb, VW, WfcB);
    k_attn<<<2048, 256, 0, stream>>>(Q, Kb, VW, AO);
    k_fc<<<1024, 256, 0, stream>>>(AO, WfcB, bfc, out);
}